// Round 2
// baseline (67.584 us; speedup 1.0000x reference)
//
#include <hip/hip_runtime.h>

// CRF forward (buggy-LSE reference) telescoped into per-token parallel form.
// Round 2: 2 tokens/thread, last-block finalize (2 dispatches total).
//
// ws layout: [0] u32 counter ; [256] 64 floats exp(trans) ; [1024] partials.

__global__ void prep_kernel(const float* __restrict__ trans, float* __restrict__ et,
                            unsigned int* __restrict__ counter) {
    int i = threadIdx.x;
    et[i] = __expf(trans[i]);
    if (i == 0) *counter = 0u;
}

__device__ __forceinline__ void compute_va(const float f[8],
                                           const float* __restrict__ trans,
                                           float va[8]) {
    float v0[8];
    #pragma unroll
    for (int b = 0; b < 8; ++b) v0[b] = f[b] + trans[b * 8];
    // row 0: keys == payloads -> payload at argmax is just the max
    va[0] = fmaxf(fmaxf(fmaxf(v0[0], v0[1]), fmaxf(v0[2], v0[3])),
                  fmaxf(fmaxf(v0[4], v0[5]), fmaxf(v0[6], v0[7])));
    #pragma unroll
    for (int a = 1; a < 8; ++a) {
        float h[8];
        #pragma unroll
        for (int b = 0; b < 8; ++b) h[b] = f[b] + trans[b * 8 + a];
        float hm = fmaxf(fmaxf(fmaxf(h[0], h[1]), fmaxf(h[2], h[3])),
                         fmaxf(fmaxf(h[4], h[5]), fmaxf(h[6], h[7])));
        float vb = v0[7];
        #pragma unroll
        for (int b = 6; b >= 0; --b) vb = (h[b] == hm) ? v0[b] : vb;  // first-argmax
        va[a] = vb;
    }
}

__device__ __forceinline__ float token_core(const float f[8], const float va[8],
                                            const float Dp[7],
                                            const float* __restrict__ et) {
    float ef[8];
    #pragma unroll
    for (int b = 0; b < 8; ++b) ef[b] = __expf(f[b]);
    float R[8] = {0, 0, 0, 0, 0, 0, 0, 0};
    #pragma unroll
    for (int b = 0; b < 8; ++b) {
        const float efb = ef[b];
        #pragma unroll
        for (int a = 0; a < 8; ++a) R[a] = fmaf(efb, et[b * 8 + a], R[a]);
    }
    float S = __expf(-va[0]) * R[0];
    #pragma unroll
    for (int a = 1; a < 8; ++a) S += __expf(Dp[a - 1] - va[a]) * R[a];
    return va[0] + __logf(S);
}

// 256 threads, each owns tokens (2*local, 2*local+1); block = 512 tokens = 4 seqs.
__global__ __launch_bounds__(256) void crf_main_kernel(
    const float* __restrict__ wf,      // [T][8]
    const int*   __restrict__ tc,      // [T]
    const float* __restrict__ trans,   // [8][8] trans[next*8+prev]
    const float* __restrict__ et,      // exp(trans) [64]
    float* __restrict__ partials,      // [nblocks]
    unsigned int* __restrict__ counter,
    float* __restrict__ out,
    int nblocks)
{
    const int local = threadIdx.x;
    const int tokA  = blockIdx.x * 512 + 2 * local;
    const int tA    = (2 * local) & 127;          // even position in sequence
    const bool activeA = (tA != 0);               // A != START
    const bool activeB = (tA != 126);             // B != STOP

    __shared__ float Dlds[7][256];
    __shared__ int   tagLds[256];
    __shared__ float red[4];
    __shared__ unsigned int lastFlag;

    // ---- loads: 64B features + 8B tags per thread ----
    const float4* wf4 = reinterpret_cast<const float4*>(wf) + (size_t)tokA * 2;
    float4 xa = wf4[0], ya = wf4[1], xb = wf4[2], yb = wf4[3];
    const float fA[8] = {xa.x, xa.y, xa.z, xa.w, ya.x, ya.y, ya.z, ya.w};
    const float fB[8] = {xb.x, xb.y, xb.z, xb.w, yb.x, yb.y, yb.z, yb.w};
    const int2 tg = *reinterpret_cast<const int2*>(tc + tokA);
    const int tagA = tg.x, tagB = tg.y;

    float vaA[8], vaB[8];
    compute_va(fA, trans, vaA);
    compute_va(fB, trans, vaB);

    // publish token B's D (read by next thread's token A) and tagA (read by prev thread's B)
    #pragma unroll
    for (int a = 1; a < 8; ++a) Dlds[a - 1][local] = vaB[a] - vaB[0];
    tagLds[local] = tagA;
    __syncthreads();

    float c = 0.0f;

    // ---- token A (needs D from LDS; inactive when tA==0) ----
    {
        const int pidx = (local == 0) ? 0 : local - 1;
        float Dp[7];
        #pragma unroll
        for (int a = 0; a < 7; ++a) Dp[a] = Dlds[a][pidx];

        float cA = token_core(fA, vaA, Dp, et);

        if (tA == 126) {  // final STOP logsumexp over D(126)
            float D1 = vaA[1] - vaA[0], D2 = vaA[2] - vaA[0], D3 = vaA[3] - vaA[0];
            float D4 = vaA[4] - vaA[0], D5 = vaA[5] - vaA[0], D6 = vaA[6] - vaA[0];
            float D7 = vaA[7] - vaA[0];
            float m = fmaxf(fmaxf(fmaxf(0.0f, D1), fmaxf(D2, D3)),
                            fmaxf(fmaxf(D4, D5), fmaxf(D6, D7)));
            float s2 = __expf(0.0f - m) + __expf(D1 - m) + __expf(D2 - m) +
                       __expf(D3 - m) + __expf(D4 - m) + __expf(D5 - m) +
                       __expf(D6 - m) + __expf(D7 - m);
            cA += m + __logf(s2);
        }
        // truth path: emit + T[tag_next, tag]; at t==126 the trans term cancels w/ STOP
        float emit = wf[(size_t)tokA * 8 + tagA];
        float tr = (tA != 126) ? trans[tagB * 8 + tagA] : 0.0f;
        cA -= emit + tr;
        c += activeA ? cA : 0.0f;
    }

    // ---- token B (D from token A's registers; D=0 if A is START) ----
    {
        float Dp[7];
        #pragma unroll
        for (int a = 0; a < 7; ++a)
            Dp[a] = activeA ? (vaA[a + 1] - vaA[0]) : 0.0f;

        float cB = token_core(fB, vaB, Dp, et);

        const int nidx = (local == 255) ? 255 : local + 1;
        const int tagN = tagLds[nidx];                 // tag of token B+1
        float emit = wf[(size_t)tokA * 8 + 8 + tagB];
        float tr = trans[tagN * 8 + tagB];             // B is never at t==126
        cB -= emit + tr;
        c += activeB ? cB : 0.0f;
    }

    // ---- block reduction ----
    #pragma unroll
    for (int off = 32; off >= 1; off >>= 1) c += __shfl_xor(c, off, 64);
    if ((local & 63) == 0) red[local >> 6] = c;
    __syncthreads();
    if (local == 0) {
        float bs = red[0] + red[1] + red[2] + red[3];
        partials[blockIdx.x] = bs;
        __threadfence();
        unsigned int old = atomicAdd(counter, 1u);
        lastFlag = (old == (unsigned)(nblocks - 1)) ? 1u : 0u;
    }
    __syncthreads();

    // ---- last block finalizes (deterministic ordered sum) ----
    if (lastFlag) {
        __threadfence();
        float s = 0.0f;
        for (int i = local; i < nblocks; i += 256) s += partials[i];
        #pragma unroll
        for (int off = 32; off >= 1; off >>= 1) s += __shfl_xor(s, off, 64);
        if ((local & 63) == 0) red[local >> 6] = s;
        __syncthreads();
        if (local == 0) out[0] = red[0] + red[1] + red[2] + red[3];
    }
}

extern "C" void kernel_launch(void* const* d_in, const int* in_sizes, int n_in,
                              void* d_out, int out_size, void* d_ws, size_t ws_size,
                              hipStream_t stream) {
    const float* wf    = (const float*)d_in[0];
    const int*   tc    = (const int*)d_in[2];
    const float* trans = (const float*)d_in[3];

    const int T = in_sizes[1];          // 1048576 tokens
    const int nblocks = T / 512;        // 2048

    unsigned int* counter = (unsigned int*)d_ws;
    float* et       = (float*)((char*)d_ws + 256);
    float* partials = (float*)((char*)d_ws + 1024);

    prep_kernel<<<1, 64, 0, stream>>>(trans, et, counter);
    crf_main_kernel<<<nblocks, 256, 0, stream>>>(wf, tc, trans, et, partials,
                                                 counter, (float*)d_out, nblocks);
}

// Round 3
// 24.013 us; speedup vs baseline: 2.8145x; 2.8145x over previous
//
#include <hip/hip_runtime.h>

// CRF forward (buggy-LSE reference) telescoped into per-token parallel form.
// R3: back to 3-dispatch structure (R2's threadfence finalize serialized block
// exit -> 86% stall). 1 token/thread; emit selected from registers; row-0
// argmax shortcut.
//
// ws layout: [0] 64 floats exp(trans) ; [1024] partials [4096].

__global__ void prep_kernel(const float* __restrict__ trans, float* __restrict__ et) {
    int i = threadIdx.x;
    et[i] = __expf(trans[i]);
}

// 256 threads = 2 sequences of 128 tokens. Thread <-> token.
__global__ __launch_bounds__(256) void crf_main_kernel(
    const float* __restrict__ wf,      // [T][8]
    const int*   __restrict__ tc,      // [T]
    const float* __restrict__ trans,   // [8][8] trans[next*8+prev]
    const float* __restrict__ et,      // exp(trans), [64]
    float* __restrict__ partials)      // [gridDim.x]
{
    const int local = threadIdx.x;
    const int tok   = blockIdx.x * 256 + local;   // global token index
    const int t     = local & 127;                // position within sequence
    const bool active = (t >= 1) && (t <= 126);   // interior tokens only

    __shared__ float Dlds[7][256];
    __shared__ float red[4];

    float f[8];
    float va[8];   // per row a: payload-at-argmax = feat[idx_a] + T[idx_a, 0]
    float c = 0.0f;

    if (active) {
        const float4* wf4 = reinterpret_cast<const float4*>(wf) + (size_t)tok * 2;
        float4 x = wf4[0];
        float4 y = wf4[1];
        f[0]=x.x; f[1]=x.y; f[2]=x.z; f[3]=x.w;
        f[4]=y.x; f[5]=y.y; f[6]=y.z; f[7]=y.w;

        // v0[b] = feat[b] + T[b,0]
        float v0[8];
        #pragma unroll
        for (int b = 0; b < 8; ++b) v0[b] = f[b] + trans[b * 8];

        // row 0: keys == payloads -> payload at argmax is just the max
        va[0] = fmaxf(fmaxf(fmaxf(v0[0], v0[1]), fmaxf(v0[2], v0[3])),
                      fmaxf(fmaxf(v0[4], v0[5]), fmaxf(v0[6], v0[7])));

        #pragma unroll
        for (int a = 1; a < 8; ++a) {
            float h[8];
            #pragma unroll
            for (int b = 0; b < 8; ++b) h[b] = f[b] + trans[b * 8 + a];
            float hm = fmaxf(fmaxf(fmaxf(h[0],h[1]), fmaxf(h[2],h[3])),
                             fmaxf(fmaxf(h[4],h[5]), fmaxf(h[6],h[7])));
            // first-argmax semantics: descending scan keeps lowest b on ties
            float vb = v0[7];
            #pragma unroll
            for (int b = 6; b >= 0; --b) vb = (h[b] == hm) ? v0[b] : vb;
            va[a] = vb;
        }
    }

    // publish D_a = va[a] - va[0] for the next token; START (t==0) publishes 0
    if (t == 0) {
        #pragma unroll
        for (int a = 1; a < 8; ++a) Dlds[a-1][local] = 0.0f;
    } else if (active) {
        #pragma unroll
        for (int a = 1; a < 8; ++a) Dlds[a-1][local] = va[a] - va[0];
    }
    __syncthreads();

    if (active) {
        float Dp[7];
        #pragma unroll
        for (int a = 1; a < 8; ++a) Dp[a-1] = Dlds[a-1][local - 1];

        float ef[8];
        #pragma unroll
        for (int b = 0; b < 8; ++b) ef[b] = __expf(f[b]);

        // R[a] = sum_b exp(feat[b]) * exp(T[b,a])   (et uniform -> scalar loads)
        float R[8] = {0,0,0,0,0,0,0,0};
        #pragma unroll
        for (int b = 0; b < 8; ++b) {
            const float efb = ef[b];
            #pragma unroll
            for (int a = 0; a < 8; ++a) R[a] = fmaf(efb, et[b * 8 + a], R[a]);
        }

        // S = sum_a exp(D_a(t-1) - va[a]) * R[a];  D_0 = 0
        float S = __expf(-va[0]) * R[0];
        #pragma unroll
        for (int a = 1; a < 8; ++a) S += __expf(Dp[a-1] - va[a]) * R[a];

        c = va[0] + __logf(S);   // v0b_0(t) + log S(t)

        // last interior token: exact logsumexp over D(126) (final STOP lse)
        if (t == 126) {
            float D[8];
            D[0] = 0.0f;
            #pragma unroll
            for (int a = 1; a < 8; ++a) D[a] = va[a] - va[0];
            float m = fmaxf(fmaxf(fmaxf(D[0],D[1]), fmaxf(D[2],D[3])),
                            fmaxf(fmaxf(D[4],D[5]), fmaxf(D[6],D[7])));
            float s2 = 0.0f;
            #pragma unroll
            for (int a = 0; a < 8; ++a) s2 += __expf(D[a] - m);
            c += m + __logf(s2);
        }

        // truth path (subtracted). tag in [0,6) for interior tokens -> select
        // emit from registers (no scattered global gather). For t==126 the
        // T[7,tag] term cancels with the STOP step's -T[7,tag_prev].
        int tag = tc[tok];
        float emit = f[0];
        #pragma unroll
        for (int b = 1; b < 6; ++b) emit = (tag == b) ? f[b] : emit;
        float tr = 0.0f;
        if (t < 126) {
            int tagn = tc[tok + 1];
            tr = trans[tagn * 8 + tag];
        }
        c -= emit + tr;
    }

    // block reduction of contributions
    #pragma unroll
    for (int off = 32; off >= 1; off >>= 1) c += __shfl_xor(c, off, 64);
    if ((local & 63) == 0) red[local >> 6] = c;
    __syncthreads();
    if (local == 0) partials[blockIdx.x] = red[0] + red[1] + red[2] + red[3];
}

// 1024 threads; n is a multiple of 4096 -> each thread loads one float4.
__global__ __launch_bounds__(1024) void reduce_kernel(
    const float* __restrict__ partials, int n, float* __restrict__ out)
{
    __shared__ float red[16];
    float s = 0.0f;
    for (int i = threadIdx.x; i * 4 < n; i += 1024) {
        float4 p = reinterpret_cast<const float4*>(partials)[i];
        s += (p.x + p.y) + (p.z + p.w);
    }
    #pragma unroll
    for (int off = 32; off >= 1; off >>= 1) s += __shfl_xor(s, off, 64);
    if ((threadIdx.x & 63) == 0) red[threadIdx.x >> 6] = s;
    __syncthreads();
    if (threadIdx.x == 0) {
        float tot = 0.0f;
        #pragma unroll
        for (int w = 0; w < 16; ++w) tot += red[w];
        out[0] = tot;
    }
}

extern "C" void kernel_launch(void* const* d_in, const int* in_sizes, int n_in,
                              void* d_out, int out_size, void* d_ws, size_t ws_size,
                              hipStream_t stream) {
    const float* wf    = (const float*)d_in[0];
    const int*   tc    = (const int*)d_in[2];
    const float* trans = (const float*)d_in[3];

    const int T = in_sizes[1];          // 8192 * 128 = 1048576 tokens
    const int nblocks = T / 256;        // 4096

    float* et       = (float*)d_ws;                      // 64 floats
    float* partials = (float*)((char*)d_ws + 1024);      // nblocks floats

    prep_kernel<<<1, 64, 0, stream>>>(trans, et);
    crf_main_kernel<<<nblocks, 256, 0, stream>>>(wf, tc, trans, et, partials);
    reduce_kernel<<<1, 1024, 0, stream>>>(partials, nblocks, (float*)d_out);
}